// Round 1
// baseline (530.314 us; speedup 1.0000x reference)
//
#include <hip/hip_runtime.h>
#include <hip/hip_bf16.h>
#include <cmath>

// Problem constants (fixed by the reference)
constexpr int T_DIM = 4096;
constexpr int H_DIM = 1024;
constexpr int E_DIM = 8;
constexpr int I_DIM = 512;   // 4096 / 8
constexpr int V_DIM = 32000;

// GEMM tiling
constexpr int BM = 32;   // tokens per block
constexpr int BN = 64;   // output cols per block
constexpr int BK = 16;   // K-slab
constexpr int LDS_STRIDE = BK + 4;  // 20 floats: keeps float4 alignment, breaks pow2 strides

// ---------------------------------------------------------------------------
// Workspace layout:
//   [0, 256)                      : counts[E]  (int)
//   [256, 256 + E*T*4)            : tok_list[E][T] (int)
//   [256 + E*T*4, +T*I*4)         : inter[T][I] (float)  ~8 MB
// ---------------------------------------------------------------------------

__global__ __launch_bounds__(64) void init_counts_kernel(int* __restrict__ counts) {
    if (threadIdx.x < E_DIM) counts[threadIdx.x] = 0;
}

__global__ __launch_bounds__(256) void route_kernel(
    const float* __restrict__ mu, const int* __restrict__ token_ids,
    const float* __restrict__ mu_w, int* __restrict__ counts,
    int* __restrict__ tok_list)
{
    const int lane = threadIdx.x & 63;
    const int wave = threadIdx.x >> 6;
    const int t = blockIdx.x * 4 + wave;
    if (t >= T_DIM) return;

    const float* mrow = mu + (size_t)t * H_DIM;
    float acc[E_DIM];
#pragma unroll
    for (int e = 0; e < E_DIM; ++e) acc[e] = 0.f;

    for (int j = lane; j < H_DIM; j += 64) {
        float m = mrow[j];
#pragma unroll
        for (int e = 0; e < E_DIM; ++e) acc[e] += m * mu_w[e * H_DIM + j];
    }
#pragma unroll
    for (int e = 0; e < E_DIM; ++e) {
#pragma unroll
        for (int off = 32; off > 0; off >>= 1)
            acc[e] += __shfl_down(acc[e], off, 64);
    }
    if (lane == 0) {
        int tid = token_ids[t];
        tid = min(max(tid, 0), V_DIM - 1);
        const int be = tid & (E_DIM - 1);
        float best = -1e30f; int bi = 0;
#pragma unroll
        for (int e = 0; e < E_DIM; ++e) {
            float c = acc[e] + (e == be ? 10.f : 0.f);
            if (c > best) { best = c; bi = e; }  // strict > keeps first max (jnp.argmax)
        }
        const int pos = atomicAdd(&counts[bi], 1);
        tok_list[bi * T_DIM + pos] = t;
    }
}

// inter[t][i] = silu(x[t] @ W[e][:, i]) * (x[t] @ W[e][:, I + i]) for tokens of expert e
__global__ __launch_bounds__(256) void gemm1_kernel(
    const float* __restrict__ x, const float* __restrict__ gup,
    const int* __restrict__ counts, const int* __restrict__ tok_list,
    float* __restrict__ inter)
{
    const int e = blockIdx.z;
    const int count = counts[e];
    const int m0 = blockIdx.y * BM;
    if (m0 >= count) return;
    const int n0 = blockIdx.x * BN;

    __shared__ int   toks[BM];
    __shared__ float Xs[BM][LDS_STRIDE];
    __shared__ float Wt[2 * BN][LDS_STRIDE];  // transposed: [col][k]; cols 0..63 gate, 64..127 up

    const int tid = threadIdx.x;
    const int tx = tid & 31;   // inter-col pair
    const int ty = tid >> 5;   // row quad

    if (tid < BM) {
        const int m = m0 + tid;
        toks[tid] = (m < count) ? tok_list[e * T_DIM + m] : -1;
    }
    __syncthreads();

    const float* We = gup + (size_t)e * H_DIM * (2 * I_DIM);

    float accg[4][2] = {};
    float accu[4][2] = {};

    for (int k0 = 0; k0 < H_DIM; k0 += BK) {
        // stage X tile: 32 rows x 16 k, float4 per thread (threads 0..127)
        if (tid < 128) {
            const int r = tid >> 2, k4 = (tid & 3) * 4;
            const int tk = toks[r];
            float4 v = make_float4(0.f, 0.f, 0.f, 0.f);
            if (tk >= 0) v = *(const float4*)&x[(size_t)tk * H_DIM + k0 + k4];
            *(float4*)&Xs[r][k4] = v;
        }
        // stage W tile: 16 k x 128 cols, transposed into Wt[col][k]
#pragma unroll
        for (int s = 0; s < 2; ++s) {
            const int q = tid + s * 256;
            const int c = q & 127, k4 = (q >> 7) * 4;
            const int col = (c < BN) ? (n0 + c) : (I_DIM + n0 + (c - BN));
            float4 v;
            v.x = We[(size_t)(k0 + k4 + 0) * (2 * I_DIM) + col];
            v.y = We[(size_t)(k0 + k4 + 1) * (2 * I_DIM) + col];
            v.z = We[(size_t)(k0 + k4 + 2) * (2 * I_DIM) + col];
            v.w = We[(size_t)(k0 + k4 + 3) * (2 * I_DIM) + col];
            *(float4*)&Wt[c][k4] = v;
        }
        __syncthreads();

#pragma unroll
        for (int kk = 0; kk < BK; kk += 4) {
            float4 xv[4];
#pragma unroll
            for (int r = 0; r < 4; ++r)
                xv[r] = *(const float4*)&Xs[ty * 4 + r][kk];
#pragma unroll
            for (int c = 0; c < 2; ++c) {
                const float4 wg = *(const float4*)&Wt[tx * 2 + c][kk];
                const float4 wu = *(const float4*)&Wt[BN + tx * 2 + c][kk];
#pragma unroll
                for (int r = 0; r < 4; ++r) {
                    accg[r][c] += xv[r].x * wg.x + xv[r].y * wg.y + xv[r].z * wg.z + xv[r].w * wg.w;
                    accu[r][c] += xv[r].x * wu.x + xv[r].y * wu.y + xv[r].z * wu.z + xv[r].w * wu.w;
                }
            }
        }
        __syncthreads();
    }

#pragma unroll
    for (int r = 0; r < 4; ++r) {
        const int tk = toks[ty * 4 + r];
        if (tk < 0) continue;
#pragma unroll
        for (int c = 0; c < 2; ++c) {
            const float g = accg[r][c], u = accu[r][c];
            const float s = g / (1.f + expf(-g));  // silu
            inter[(size_t)tk * I_DIM + n0 + tx * 2 + c] = s * u;
        }
    }
}

// out[t][:] = inter[t] @ down[e]
__global__ __launch_bounds__(256) void gemm2_kernel(
    const float* __restrict__ inter, const float* __restrict__ down,
    const int* __restrict__ counts, const int* __restrict__ tok_list,
    float* __restrict__ out)
{
    const int e = blockIdx.z;
    const int count = counts[e];
    const int m0 = blockIdx.y * BM;
    if (m0 >= count) return;
    const int n0 = blockIdx.x * BN;

    __shared__ int   toks[BM];
    __shared__ float Is[BM][LDS_STRIDE];
    __shared__ float Dt[BN][LDS_STRIDE];  // transposed [col][k]

    const int tid = threadIdx.x;
    const int tx = tid & 31;
    const int ty = tid >> 5;

    if (tid < BM) {
        const int m = m0 + tid;
        toks[tid] = (m < count) ? tok_list[e * T_DIM + m] : -1;
    }
    __syncthreads();

    const float* De = down + (size_t)e * I_DIM * H_DIM;
    float acc[4][2] = {};

    for (int k0 = 0; k0 < I_DIM; k0 += BK) {
        if (tid < 128) {
            const int r = tid >> 2, k4 = (tid & 3) * 4;
            const int tk = toks[r];
            float4 v = make_float4(0.f, 0.f, 0.f, 0.f);
            if (tk >= 0) v = *(const float4*)&inter[(size_t)tk * I_DIM + k0 + k4];
            *(float4*)&Is[r][k4] = v;
        }
        {
            const int c = tid & 63, k4 = (tid >> 6) * 4;
            float4 v;
            v.x = De[(size_t)(k0 + k4 + 0) * H_DIM + n0 + c];
            v.y = De[(size_t)(k0 + k4 + 1) * H_DIM + n0 + c];
            v.z = De[(size_t)(k0 + k4 + 2) * H_DIM + n0 + c];
            v.w = De[(size_t)(k0 + k4 + 3) * H_DIM + n0 + c];
            *(float4*)&Dt[c][k4] = v;
        }
        __syncthreads();

#pragma unroll
        for (int kk = 0; kk < BK; kk += 4) {
            float4 xv[4];
#pragma unroll
            for (int r = 0; r < 4; ++r)
                xv[r] = *(const float4*)&Is[ty * 4 + r][kk];
#pragma unroll
            for (int c = 0; c < 2; ++c) {
                const float4 wd = *(const float4*)&Dt[tx * 2 + c][kk];
#pragma unroll
                for (int r = 0; r < 4; ++r)
                    acc[r][c] += xv[r].x * wd.x + xv[r].y * wd.y + xv[r].z * wd.z + xv[r].w * wd.w;
            }
        }
        __syncthreads();
    }

#pragma unroll
    for (int r = 0; r < 4; ++r) {
        const int tk = toks[ty * 4 + r];
        if (tk < 0) continue;
#pragma unroll
        for (int c = 0; c < 2; ++c)
            out[(size_t)tk * H_DIM + n0 + tx * 2 + c] = acc[r][c];
    }
}

extern "C" void kernel_launch(void* const* d_in, const int* in_sizes, int n_in,
                              void* d_out, int out_size, void* d_ws, size_t ws_size,
                              hipStream_t stream)
{
    const float* x         = (const float*)d_in[0];
    const int*   token_ids = (const int*)  d_in[1];
    const float* mu        = (const float*)d_in[2];
    const float* gup       = (const float*)d_in[3];
    const float* down      = (const float*)d_in[4];
    const float* mu_w      = (const float*)d_in[5];
    float* out = (float*)d_out;

    char* ws = (char*)d_ws;
    int*   counts   = (int*)ws;                                   // 256 B
    int*   tok_list = (int*)(ws + 256);                           // E*T*4 = 128 KB
    float* inter    = (float*)(ws + 256 + E_DIM * T_DIM * 4);     // T*I*4 = 8 MB

    init_counts_kernel<<<1, 64, 0, stream>>>(counts);
    route_kernel<<<T_DIM / 4, 256, 0, stream>>>(mu, token_ids, mu_w, counts, tok_list);
    gemm1_kernel<<<dim3(I_DIM / BN, T_DIM / BM, E_DIM), 256, 0, stream>>>(
        x, gup, counts, tok_list, inter);
    gemm2_kernel<<<dim3(H_DIM / BN, T_DIM / BM, E_DIM), 256, 0, stream>>>(
        inter, down, counts, tok_list, out);
}

// Round 2
// 231.504 us; speedup vs baseline: 2.2907x; 2.2907x over previous
//
#include <hip/hip_runtime.h>
#include <cmath>

// Problem constants (fixed by the reference)
constexpr int T_DIM = 4096;
constexpr int H_DIM = 1024;
constexpr int E_DIM = 8;
constexpr int I_DIM = 512;   // 4096 / 8
constexpr int V_DIM = 32000;

typedef _Float16 half_t;
typedef __attribute__((ext_vector_type(8))) _Float16 halfx8;
typedef __attribute__((ext_vector_type(4))) _Float16 halfx4;
typedef __attribute__((ext_vector_type(4))) float floatx4;

// ---------------------------------------------------------------------------
// Workspace layout (bytes)
// ---------------------------------------------------------------------------
constexpr size_t OFF_COUNTS = 0;                                         // E ints
constexpr size_t OFF_TOKL   = 1024;                                      // E*T ints
constexpr size_t OFF_XB     = OFF_TOKL + (size_t)E_DIM * T_DIM * 4;      // T*H f16
constexpr size_t OFF_GUPT   = OFF_XB + (size_t)T_DIM * H_DIM * 2;        // E*2I*H f16 (transposed)
constexpr size_t OFF_DOWNT  = OFF_GUPT + (size_t)E_DIM * 2 * I_DIM * H_DIM * 2; // E*H*I f16 (transposed)
constexpr size_t OFF_INTER  = OFF_DOWNT + (size_t)E_DIM * H_DIM * I_DIM * 2;    // T*I f16
constexpr size_t WS_NEEDED  = OFF_INTER + (size_t)T_DIM * I_DIM * 2;     // ~36.1 MB

// ---------------------------------------------------------------------------
// Routing
// ---------------------------------------------------------------------------
__global__ __launch_bounds__(64) void init_counts_kernel(int* __restrict__ counts) {
    if (threadIdx.x < E_DIM) counts[threadIdx.x] = 0;
}

__global__ __launch_bounds__(256) void route_kernel(
    const float* __restrict__ mu, const int* __restrict__ token_ids,
    const float* __restrict__ mu_w, int* __restrict__ counts,
    int* __restrict__ tok_list)
{
    const int lane = threadIdx.x & 63;
    const int wave = threadIdx.x >> 6;
    const int t = blockIdx.x * 4 + wave;
    if (t >= T_DIM) return;

    const float* mrow = mu + (size_t)t * H_DIM;
    float acc[E_DIM];
#pragma unroll
    for (int e = 0; e < E_DIM; ++e) acc[e] = 0.f;

    for (int j = lane; j < H_DIM; j += 64) {
        float m = mrow[j];
#pragma unroll
        for (int e = 0; e < E_DIM; ++e) acc[e] += m * mu_w[e * H_DIM + j];
    }
#pragma unroll
    for (int e = 0; e < E_DIM; ++e) {
#pragma unroll
        for (int off = 32; off > 0; off >>= 1)
            acc[e] += __shfl_down(acc[e], off, 64);
    }
    if (lane == 0) {
        int tid = token_ids[t];
        tid = min(max(tid, 0), V_DIM - 1);
        const int be = tid & (E_DIM - 1);
        float best = -1e30f; int bi = 0;
#pragma unroll
        for (int e = 0; e < E_DIM; ++e) {
            float c = acc[e] + (e == be ? 10.f : 0.f);
            if (c > best) { best = c; bi = e; }  // strict > keeps first max (jnp.argmax)
        }
        const int pos = atomicAdd(&counts[bi], 1);
        tok_list[bi * T_DIM + pos] = t;
    }
}

// ---------------------------------------------------------------------------
// Conversion pre-passes
// ---------------------------------------------------------------------------
__global__ __launch_bounds__(256) void convert_x_kernel(
    const float* __restrict__ x, half_t* __restrict__ xb)
{
    const int i = blockIdx.x * 256 + threadIdx.x;   // group of 4 elems
    const float4 v = ((const float4*)x)[i];
    halfx4 h = { (half_t)v.x, (half_t)v.y, (half_t)v.z, (half_t)v.w };
    *(halfx4*)(xb + (size_t)i * 4) = h;
}

// dst[e][n][k] = (f16) src[e][k][n];  K = src rows, N = src cols
__global__ __launch_bounds__(256) void transpose_cvt_kernel(
    const float* __restrict__ src, half_t* __restrict__ dst, int K, int N)
{
    const int e = blockIdx.z;
    const float* se = src + (size_t)e * K * N;
    half_t* de = dst + (size_t)e * K * N;
    const int n0 = blockIdx.x * 32, k0 = blockIdx.y * 32;
    __shared__ float tile[32][33];
    const int c = threadIdx.x & 31, r0 = threadIdx.x >> 5;
#pragma unroll
    for (int p = 0; p < 4; ++p) {
        const int r = r0 + p * 8;
        tile[r][c] = se[(size_t)(k0 + r) * N + n0 + c];
    }
    __syncthreads();
#pragma unroll
    for (int p = 0; p < 4; ++p) {
        const int r = r0 + p * 8;
        de[(size_t)(n0 + r) * K + k0 + c] = (half_t)tile[c][r];
    }
}

// ---------------------------------------------------------------------------
// MFMA GEMM 1: inter[t][i] = silu(x@Wg) * (x@Wu), f16 in / f32 acc / f16 out
// Block tile 64 tokens x (64 gate + 64 up) cols, BK=64. 4 waves in 2x2.
// LDS rows padded to 72 halves (144 B): frag reads 2-way bank aliased (free).
// ---------------------------------------------------------------------------
__global__ __launch_bounds__(256) void gemm1_mfma_kernel(
    const half_t* __restrict__ xb, const half_t* __restrict__ gupT,
    const int* __restrict__ counts, const int* __restrict__ tok_list,
    half_t* __restrict__ inter)
{
    const int e = blockIdx.z;
    const int count = counts[e];
    const int m0 = blockIdx.y * 64;
    if (m0 >= count) return;
    const int n0 = blockIdx.x * 64;  // gate col block

    __shared__ half_t As[64 * 72];
    __shared__ half_t Bs[128 * 72];
    __shared__ int toks[64];
    __shared__ int tokeff[64];

    const int tid = threadIdx.x;
    if (tid < 64) {
        const int m = m0 + tid;
        const int tk = (m < count) ? tok_list[e * T_DIM + m] : -1;
        toks[tid] = tk;
        tokeff[tid] = (tk < 0) ? 0 : tk;   // pad rows load token 0, store masked
    }
    __syncthreads();

    const half_t* We = gupT + (size_t)e * (2 * I_DIM) * H_DIM;

    const floatx4 fzero = {0.f, 0.f, 0.f, 0.f};
    floatx4 accg[2][2], accu[2][2];
#pragma unroll
    for (int i = 0; i < 2; ++i)
#pragma unroll
        for (int j = 0; j < 2; ++j) { accg[i][j] = fzero; accu[i][j] = fzero; }

    const int lane = tid & 63;
    const int w = tid >> 6;
    const int wr = w >> 1, wc = w & 1;       // wave grid 2x2
    const int fm = lane & 15, q = lane >> 4; // fragment row/col + k-quad
    const int sc = tid & 7, sr = tid >> 3;   // staging chunk / row

    for (int k0 = 0; k0 < H_DIM; k0 += 64) {
#pragma unroll
        for (int j = 0; j < 2; ++j) {
            const int r = sr + 32 * j;
            *(int4*)&As[r * 72 + sc * 8] =
                *(const int4*)(xb + (size_t)tokeff[r] * H_DIM + k0 + sc * 8);
        }
#pragma unroll
        for (int j = 0; j < 4; ++j) {
            const int n = sr + 32 * j;
            const int col = (n < 64) ? (n0 + n) : (I_DIM + n0 + (n - 64));
            *(int4*)&Bs[n * 72 + sc * 8] =
                *(const int4*)(We + (size_t)col * H_DIM + k0 + sc * 8);
        }
        __syncthreads();

#pragma unroll
        for (int ks = 0; ks < 2; ++ks) {
            const int kc = (ks * 4 + q) * 8;
            const halfx8 a0 = *(const halfx8*)&As[(32 * wr + fm) * 72 + kc];
            const halfx8 a1 = *(const halfx8*)&As[(32 * wr + 16 + fm) * 72 + kc];
#pragma unroll
            for (int ct = 0; ct < 2; ++ct) {
                const int ng = wc * 32 + ct * 16 + fm;
                const halfx8 bg = *(const halfx8*)&Bs[ng * 72 + kc];
                const halfx8 bu = *(const halfx8*)&Bs[(64 + ng) * 72 + kc];
                accg[0][ct] = __builtin_amdgcn_mfma_f32_16x16x32_f16(a0, bg, accg[0][ct], 0, 0, 0);
                accg[1][ct] = __builtin_amdgcn_mfma_f32_16x16x32_f16(a1, bg, accg[1][ct], 0, 0, 0);
                accu[0][ct] = __builtin_amdgcn_mfma_f32_16x16x32_f16(a0, bu, accu[0][ct], 0, 0, 0);
                accu[1][ct] = __builtin_amdgcn_mfma_f32_16x16x32_f16(a1, bu, accu[1][ct], 0, 0, 0);
            }
        }
        __syncthreads();
    }

    // C/D layout: col = lane&15, row = q*4 + reg
#pragma unroll
    for (int rt = 0; rt < 2; ++rt)
#pragma unroll
        for (int r = 0; r < 4; ++r) {
            const int row = 32 * wr + 16 * rt + q * 4 + r;
            const int tk = toks[row];
            if (tk < 0) continue;
#pragma unroll
            for (int ct = 0; ct < 2; ++ct) {
                const float g = accg[rt][ct][r];
                const float u = accu[rt][ct][r];
                const float s = g / (1.f + __expf(-g)) * u;
                inter[(size_t)tk * I_DIM + n0 + wc * 32 + ct * 16 + fm] = (half_t)s;
            }
        }
}

// ---------------------------------------------------------------------------
// MFMA GEMM 2: out[t][:] = inter[t] @ down[e], block 64 x 128, BK=64
// ---------------------------------------------------------------------------
__global__ __launch_bounds__(256) void gemm2_mfma_kernel(
    const half_t* __restrict__ inter, const half_t* __restrict__ downT,
    const int* __restrict__ counts, const int* __restrict__ tok_list,
    float* __restrict__ out)
{
    const int e = blockIdx.z;
    const int count = counts[e];
    const int m0 = blockIdx.y * 64;
    if (m0 >= count) return;
    const int n0 = blockIdx.x * 128;

    __shared__ half_t As[64 * 72];
    __shared__ half_t Bs[128 * 72];
    __shared__ int toks[64];
    __shared__ int tokeff[64];

    const int tid = threadIdx.x;
    if (tid < 64) {
        const int m = m0 + tid;
        const int tk = (m < count) ? tok_list[e * T_DIM + m] : -1;
        toks[tid] = tk;
        tokeff[tid] = (tk < 0) ? 0 : tk;
    }
    __syncthreads();

    const half_t* De = downT + (size_t)e * H_DIM * I_DIM;

    const floatx4 fzero = {0.f, 0.f, 0.f, 0.f};
    floatx4 acc[2][4];
#pragma unroll
    for (int i = 0; i < 2; ++i)
#pragma unroll
        for (int j = 0; j < 4; ++j) acc[i][j] = fzero;

    const int lane = tid & 63;
    const int w = tid >> 6;
    const int wr = w >> 1, wc = w & 1;
    const int fm = lane & 15, q = lane >> 4;
    const int sc = tid & 7, sr = tid >> 3;

    for (int k0 = 0; k0 < I_DIM; k0 += 64) {
#pragma unroll
        for (int j = 0; j < 2; ++j) {
            const int r = sr + 32 * j;
            *(int4*)&As[r * 72 + sc * 8] =
                *(const int4*)(inter + (size_t)tokeff[r] * I_DIM + k0 + sc * 8);
        }
#pragma unroll
        for (int j = 0; j < 4; ++j) {
            const int n = sr + 32 * j;
            *(int4*)&Bs[n * 72 + sc * 8] =
                *(const int4*)(De + (size_t)(n0 + n) * I_DIM + k0 + sc * 8);
        }
        __syncthreads();

#pragma unroll
        for (int ks = 0; ks < 2; ++ks) {
            const int kc = (ks * 4 + q) * 8;
            const halfx8 a0 = *(const halfx8*)&As[(32 * wr + fm) * 72 + kc];
            const halfx8 a1 = *(const halfx8*)&As[(32 * wr + 16 + fm) * 72 + kc];
#pragma unroll
            for (int ct = 0; ct < 4; ++ct) {
                const halfx8 b = *(const halfx8*)&Bs[(wc * 64 + ct * 16 + fm) * 72 + kc];
                acc[0][ct] = __builtin_amdgcn_mfma_f32_16x16x32_f16(a0, b, acc[0][ct], 0, 0, 0);
                acc[1][ct] = __builtin_amdgcn_mfma_f32_16x16x32_f16(a1, b, acc[1][ct], 0, 0, 0);
            }
        }
        __syncthreads();
    }

#pragma unroll
    for (int rt = 0; rt < 2; ++rt)
#pragma unroll
        for (int r = 0; r < 4; ++r) {
            const int row = 32 * wr + 16 * rt + q * 4 + r;
            const int tk = toks[row];
            if (tk < 0) continue;
#pragma unroll
            for (int ct = 0; ct < 4; ++ct)
                out[(size_t)tk * H_DIM + n0 + wc * 64 + ct * 16 + fm] = acc[rt][ct][r];
        }
}

// ---------------------------------------------------------------------------
// Fallback fp32 path (used only if ws_size is too small for the f16 buffers)
// ---------------------------------------------------------------------------
constexpr int FBM = 32;
constexpr int FBN = 64;
constexpr int FBK = 16;
constexpr int FLS = FBK + 4;

__global__ __launch_bounds__(256) void gemm1_f32_kernel(
    const float* __restrict__ x, const float* __restrict__ gup,
    const int* __restrict__ counts, const int* __restrict__ tok_list,
    float* __restrict__ inter)
{
    const int e = blockIdx.z;
    const int count = counts[e];
    const int m0 = blockIdx.y * FBM;
    if (m0 >= count) return;
    const int n0 = blockIdx.x * FBN;

    __shared__ int   toks[FBM];
    __shared__ float Xs[FBM][FLS];
    __shared__ float Wt[2 * FBN][FLS];

    const int tid = threadIdx.x;
    const int tx = tid & 31, ty = tid >> 5;

    if (tid < FBM) {
        const int m = m0 + tid;
        toks[tid] = (m < count) ? tok_list[e * T_DIM + m] : -1;
    }
    __syncthreads();

    const float* We = gup + (size_t)e * H_DIM * (2 * I_DIM);
    float accg[4][2] = {}, accu[4][2] = {};

    for (int k0 = 0; k0 < H_DIM; k0 += FBK) {
        if (tid < 128) {
            const int r = tid >> 2, k4 = (tid & 3) * 4;
            const int tk = toks[r];
            float4 v = make_float4(0.f, 0.f, 0.f, 0.f);
            if (tk >= 0) v = *(const float4*)&x[(size_t)tk * H_DIM + k0 + k4];
            *(float4*)&Xs[r][k4] = v;
        }
#pragma unroll
        for (int s = 0; s < 2; ++s) {
            const int qq = tid + s * 256;
            const int c = qq & 127, k4 = (qq >> 7) * 4;
            const int col = (c < FBN) ? (n0 + c) : (I_DIM + n0 + (c - FBN));
            float4 v;
            v.x = We[(size_t)(k0 + k4 + 0) * (2 * I_DIM) + col];
            v.y = We[(size_t)(k0 + k4 + 1) * (2 * I_DIM) + col];
            v.z = We[(size_t)(k0 + k4 + 2) * (2 * I_DIM) + col];
            v.w = We[(size_t)(k0 + k4 + 3) * (2 * I_DIM) + col];
            *(float4*)&Wt[c][k4] = v;
        }
        __syncthreads();
#pragma unroll
        for (int kk = 0; kk < FBK; kk += 4) {
            float4 xv[4];
#pragma unroll
            for (int r = 0; r < 4; ++r) xv[r] = *(const float4*)&Xs[ty * 4 + r][kk];
#pragma unroll
            for (int c = 0; c < 2; ++c) {
                const float4 wg = *(const float4*)&Wt[tx * 2 + c][kk];
                const float4 wu = *(const float4*)&Wt[FBN + tx * 2 + c][kk];
#pragma unroll
                for (int r = 0; r < 4; ++r) {
                    accg[r][c] += xv[r].x * wg.x + xv[r].y * wg.y + xv[r].z * wg.z + xv[r].w * wg.w;
                    accu[r][c] += xv[r].x * wu.x + xv[r].y * wu.y + xv[r].z * wu.z + xv[r].w * wu.w;
                }
            }
        }
        __syncthreads();
    }
#pragma unroll
    for (int r = 0; r < 4; ++r) {
        const int tk = toks[ty * 4 + r];
        if (tk < 0) continue;
#pragma unroll
        for (int c = 0; c < 2; ++c) {
            const float g = accg[r][c], u = accu[r][c];
            inter[(size_t)tk * I_DIM + n0 + tx * 2 + c] = g / (1.f + expf(-g)) * u;
        }
    }
}

__global__ __launch_bounds__(256) void gemm2_f32_kernel(
    const float* __restrict__ inter, const float* __restrict__ down,
    const int* __restrict__ counts, const int* __restrict__ tok_list,
    float* __restrict__ out)
{
    const int e = blockIdx.z;
    const int count = counts[e];
    const int m0 = blockIdx.y * FBM;
    if (m0 >= count) return;
    const int n0 = blockIdx.x * FBN;

    __shared__ int   toks[FBM];
    __shared__ float Is[FBM][FLS];
    __shared__ float Dt[FBN][FLS];

    const int tid = threadIdx.x;
    const int tx = tid & 31, ty = tid >> 5;

    if (tid < FBM) {
        const int m = m0 + tid;
        toks[tid] = (m < count) ? tok_list[e * T_DIM + m] : -1;
    }
    __syncthreads();

    const float* De = down + (size_t)e * I_DIM * H_DIM;
    float acc[4][2] = {};

    for (int k0 = 0; k0 < I_DIM; k0 += FBK) {
        if (tid < 128) {
            const int r = tid >> 2, k4 = (tid & 3) * 4;
            const int tk = toks[r];
            float4 v = make_float4(0.f, 0.f, 0.f, 0.f);
            if (tk >= 0) v = *(const float4*)&inter[(size_t)tk * I_DIM + k0 + k4];
            *(float4*)&Is[r][k4] = v;
        }
        {
            const int c = tid & 63, k4 = (tid >> 6) * 4;
            float4 v;
            v.x = De[(size_t)(k0 + k4 + 0) * H_DIM + n0 + c];
            v.y = De[(size_t)(k0 + k4 + 1) * H_DIM + n0 + c];
            v.z = De[(size_t)(k0 + k4 + 2) * H_DIM + n0 + c];
            v.w = De[(size_t)(k0 + k4 + 3) * H_DIM + n0 + c];
            *(float4*)&Dt[c][k4] = v;
        }
        __syncthreads();
#pragma unroll
        for (int kk = 0; kk < FBK; kk += 4) {
            float4 xv[4];
#pragma unroll
            for (int r = 0; r < 4; ++r) xv[r] = *(const float4*)&Is[ty * 4 + r][kk];
#pragma unroll
            for (int c = 0; c < 2; ++c) {
                const float4 wd = *(const float4*)&Dt[tx * 2 + c][kk];
#pragma unroll
                for (int r = 0; r < 4; ++r)
                    acc[r][c] += xv[r].x * wd.x + xv[r].y * wd.y + xv[r].z * wd.z + xv[r].w * wd.w;
            }
        }
        __syncthreads();
    }
#pragma unroll
    for (int r = 0; r < 4; ++r) {
        const int tk = toks[ty * 4 + r];
        if (tk < 0) continue;
#pragma unroll
        for (int c = 0; c < 2; ++c)
            out[(size_t)tk * H_DIM + n0 + tx * 2 + c] = acc[r][c];
    }
}

// ---------------------------------------------------------------------------
extern "C" void kernel_launch(void* const* d_in, const int* in_sizes, int n_in,
                              void* d_out, int out_size, void* d_ws, size_t ws_size,
                              hipStream_t stream)
{
    const float* x         = (const float*)d_in[0];
    const int*   token_ids = (const int*)  d_in[1];
    const float* mu        = (const float*)d_in[2];
    const float* gup       = (const float*)d_in[3];
    const float* down      = (const float*)d_in[4];
    const float* mu_w      = (const float*)d_in[5];
    float* out = (float*)d_out;

    char* ws = (char*)d_ws;
    int* counts   = (int*)(ws + OFF_COUNTS);
    int* tok_list = (int*)(ws + OFF_TOKL);

    init_counts_kernel<<<1, 64, 0, stream>>>(counts);
    route_kernel<<<T_DIM / 4, 256, 0, stream>>>(mu, token_ids, mu_w, counts, tok_list);

    if (ws_size >= WS_NEEDED) {
        half_t* xb    = (half_t*)(ws + OFF_XB);
        half_t* gupT  = (half_t*)(ws + OFF_GUPT);
        half_t* downT = (half_t*)(ws + OFF_DOWNT);
        half_t* inter = (half_t*)(ws + OFF_INTER);

        convert_x_kernel<<<T_DIM * H_DIM / 1024, 256, 0, stream>>>(x, xb);
        transpose_cvt_kernel<<<dim3(2 * I_DIM / 32, H_DIM / 32, E_DIM), 256, 0, stream>>>(
            gup, gupT, H_DIM, 2 * I_DIM);
        transpose_cvt_kernel<<<dim3(H_DIM / 32, I_DIM / 32, E_DIM), 256, 0, stream>>>(
            down, downT, I_DIM, H_DIM);

        gemm1_mfma_kernel<<<dim3(8, 64, 8), 256, 0, stream>>>(xb, gupT, counts, tok_list, inter);
        gemm2_mfma_kernel<<<dim3(8, 64, 8), 256, 0, stream>>>(inter, downT, counts, tok_list, out);
    } else {
        float* interf = (float*)(ws + OFF_XB);  // 8 MB, fits the round-1 budget
        gemm1_f32_kernel<<<dim3(I_DIM / FBN, T_DIM / FBM, E_DIM), 256, 0, stream>>>(
            x, gup, counts, tok_list, interf);
        gemm2_f32_kernel<<<dim3(H_DIM / FBN, T_DIM / FBM, E_DIM), 256, 0, stream>>>(
            interf, down, counts, tok_list, out);
    }
}

// Round 3
// 222.719 us; speedup vs baseline: 2.3811x; 1.0394x over previous
//
#include <hip/hip_runtime.h>
#include <cmath>

// Problem constants (fixed by the reference)
constexpr int T_DIM = 4096;
constexpr int H_DIM = 1024;
constexpr int E_DIM = 8;
constexpr int I_DIM = 512;   // 4096 / 8
constexpr int V_DIM = 32000;

typedef _Float16 half_t;
typedef __attribute__((ext_vector_type(8))) _Float16 halfx8;
typedef __attribute__((ext_vector_type(4))) _Float16 halfx4;
typedef __attribute__((ext_vector_type(4))) float floatx4;

// async global->LDS, 16 B per lane; LDS dest is wave-uniform base + lane*16
#define GLOAD16(g, l)                                                        \
    __builtin_amdgcn_global_load_lds(                                        \
        (const __attribute__((address_space(1))) void*)(g),                  \
        (__attribute__((address_space(3))) void*)(l), 16, 0, 0)

// ---------------------------------------------------------------------------
// Workspace layout (bytes)
// ---------------------------------------------------------------------------
constexpr size_t OFF_COUNTS = 0;                                         // E ints
constexpr size_t OFF_TOKL   = 1024;                                      // E*T ints
constexpr size_t OFF_XB     = OFF_TOKL + (size_t)E_DIM * T_DIM * 4;      // T*H f16
constexpr size_t OFF_GUPT   = OFF_XB + (size_t)T_DIM * H_DIM * 2;        // E*2I*H f16 (transposed)
constexpr size_t OFF_DOWNT  = OFF_GUPT + (size_t)E_DIM * 2 * I_DIM * H_DIM * 2; // E*H*I f16 (transposed)
constexpr size_t OFF_INTER  = OFF_DOWNT + (size_t)E_DIM * H_DIM * I_DIM * 2;    // T*I f16

// ---------------------------------------------------------------------------
// Routing: one block per token, 256 threads, float4 loads.
// ---------------------------------------------------------------------------
__global__ __launch_bounds__(256) void route_kernel(
    const float* __restrict__ mu, const int* __restrict__ token_ids,
    const float* __restrict__ mu_w, int* __restrict__ counts,
    int* __restrict__ tok_list)
{
    const int t = blockIdx.x;
    const int tid = threadIdx.x;

    const float4 m = *(const float4*)&mu[(size_t)t * H_DIM + tid * 4];
    float acc[E_DIM];
#pragma unroll
    for (int e = 0; e < E_DIM; ++e) {
        const float4 w = *(const float4*)&mu_w[e * H_DIM + tid * 4];
        acc[e] = m.x * w.x + m.y * w.y + m.z * w.z + m.w * w.w;
    }
#pragma unroll
    for (int e = 0; e < E_DIM; ++e) {
#pragma unroll
        for (int off = 32; off > 0; off >>= 1)
            acc[e] += __shfl_down(acc[e], off, 64);
    }
    __shared__ float part[4][E_DIM];
    const int lane = tid & 63, w = tid >> 6;
    if (lane == 0) {
#pragma unroll
        for (int e = 0; e < E_DIM; ++e) part[w][e] = acc[e];
    }
    __syncthreads();
    if (tid == 0) {
        int tk = token_ids[t];
        tk = min(max(tk, 0), V_DIM - 1);
        const int be = tk & (E_DIM - 1);
        float best = -1e30f; int bi = 0;
#pragma unroll
        for (int e = 0; e < E_DIM; ++e) {
            const float c = part[0][e] + part[1][e] + part[2][e] + part[3][e]
                          + (e == be ? 10.f : 0.f);
            if (c > best) { best = c; bi = e; }  // strict > keeps first max (jnp.argmax)
        }
        const int pos = atomicAdd(&counts[bi], 1);
        tok_list[bi * T_DIM + pos] = t;
    }
}

// ---------------------------------------------------------------------------
// Fused prep: z<8 gup-transpose, z in [8,16) down-transpose, z==16 x-convert.
// Transposes: dst[e][n][k] = (f16) src[e][k][n], 64x64 tiles.
// ---------------------------------------------------------------------------
__global__ __launch_bounds__(256) void prep_kernel(
    const float* __restrict__ x, const float* __restrict__ gup,
    const float* __restrict__ down, half_t* __restrict__ xb,
    half_t* __restrict__ gupT, half_t* __restrict__ downT)
{
    __shared__ float tile[64][65];
    const int z = blockIdx.z, tid = threadIdx.x;

    if (z == 16) {  // convert x -> f16
        const int blk = blockIdx.y * 16 + blockIdx.x;   // 0..255
#pragma unroll
        for (int p = 0; p < 16; ++p) {
            const size_t i = (size_t)blk * 16384 + p * 1024 + tid * 4;
            const float4 v = *(const float4*)&x[i];
            halfx4 h = { (half_t)v.x, (half_t)v.y, (half_t)v.z, (half_t)v.w };
            *(halfx4*)&xb[i] = h;
        }
        return;
    }

    const float* se;  half_t* de;  int K;
    if (z < 8) {
        se = gup + (size_t)z * H_DIM * (2 * I_DIM);
        de = gupT + (size_t)z * (2 * I_DIM) * H_DIM;
        K = H_DIM;                       // 1024; N = 1024
    } else {
        if (blockIdx.y >= 8) return;     // K=512 -> only 8 y-tiles
        const int e = z - 8;
        se = down + (size_t)e * I_DIM * H_DIM;
        de = downT + (size_t)e * H_DIM * I_DIM;
        K = I_DIM;                       // 512; N = 1024
    }
    constexpr int N = 1024;
    const int n0 = blockIdx.x * 64, k0 = blockIdx.y * 64;
    const int c4 = (tid & 15) * 4, r0 = tid >> 4;
#pragma unroll
    for (int p = 0; p < 4; ++p) {
        const int r = r0 + p * 16;
        const float4 v = *(const float4*)&se[(size_t)(k0 + r) * N + n0 + c4];
        tile[r][c4 + 0] = v.x; tile[r][c4 + 1] = v.y;
        tile[r][c4 + 2] = v.z; tile[r][c4 + 3] = v.w;
    }
    __syncthreads();
#pragma unroll
    for (int p = 0; p < 4; ++p) {
        const int n = r0 + p * 16;
        const int kc = (tid & 15) * 4;
        halfx4 h = { (half_t)tile[kc + 0][n], (half_t)tile[kc + 1][n],
                     (half_t)tile[kc + 2][n], (half_t)tile[kc + 3][n] };
        *(halfx4*)&de[(size_t)(n0 + n) * K + k0 + kc] = h;
    }
}

// ---------------------------------------------------------------------------
// MFMA GEMM 1: inter = silu(x@Wg) * (x@Wu). Tile 64 tok x (64g + 64u), BK=64.
// Staging via global_load_lds(16B). LDS layout XOR-swizzled:
//   element (row r, 16B-chunk c) at byte offset r*128 + ((c ^ (r&7))*16)
// -> staging is lane-contiguous (HW requirement), frag reads conflict-free.
// ---------------------------------------------------------------------------
__global__ __launch_bounds__(256) void gemm1_mfma_kernel(
    const half_t* __restrict__ xb, const half_t* __restrict__ gupT,
    const int* __restrict__ counts, const int* __restrict__ tok_list,
    half_t* __restrict__ inter)
{
    const int e = blockIdx.z;
    const int count = counts[e];
    const int m0 = blockIdx.y * 64;
    if (m0 >= count) return;
    const int n0 = blockIdx.x * 64;  // gate col block

    __shared__ __align__(16) half_t As[64 * 64];
    __shared__ __align__(16) half_t Bs[128 * 64];
    __shared__ int toks[64];

    const int tid = threadIdx.x;
    if (tid < 64) {
        const int m = m0 + tid;
        toks[tid] = (m < count) ? tok_list[e * T_DIM + m] : -1;
    }
    __syncthreads();

    const half_t* We = gupT + (size_t)e * (2 * I_DIM) * H_DIM;

    const int lane = tid & 63;
    const int w = tid >> 6;
    const int lr = lane >> 3, lc = lane & 7;

    // per-lane staging pointers (row fixed across K-loop)
    const half_t* aptr[2]; const half_t* bptr[4];
    half_t *alds[2], *blds[4];
#pragma unroll
    for (int j = 0; j < 2; ++j) {                 // A rows [w*16, w*16+16)
        const int r = w * 16 + j * 8 + lr;
        const int cg = lc ^ (r & 7);
        const int tk = toks[r];
        aptr[j] = xb + (size_t)(tk < 0 ? 0 : tk) * H_DIM + cg * 8;
        alds[j] = &As[(w * 16 + j * 8) * 64];
    }
#pragma unroll
    for (int j = 0; j < 4; ++j) {                 // B rows [w*32, w*32+32)
        const int n = w * 32 + j * 8 + lr;
        const int col = (n < 64) ? (n0 + n) : (I_DIM + n0 + (n - 64));
        const int cg = lc ^ (n & 7);
        bptr[j] = We + (size_t)col * H_DIM + cg * 8;
        blds[j] = &Bs[(w * 32 + j * 8) * 64];
    }

    const floatx4 fzero = {0.f, 0.f, 0.f, 0.f};
    floatx4 accg[2][2], accu[2][2];
#pragma unroll
    for (int i = 0; i < 2; ++i)
#pragma unroll
        for (int j = 0; j < 2; ++j) { accg[i][j] = fzero; accu[i][j] = fzero; }

    const int wr = w >> 1, wc = w & 1;
    const int fm = lane & 15, q = lane >> 4;
    const int fm7 = fm & 7;

    for (int k0 = 0; k0 < H_DIM; k0 += 64) {
#pragma unroll
        for (int j = 0; j < 2; ++j) GLOAD16(aptr[j] + k0, alds[j]);
#pragma unroll
        for (int j = 0; j < 4; ++j) GLOAD16(bptr[j] + k0, blds[j]);
        __syncthreads();

#pragma unroll
        for (int ks = 0; ks < 2; ++ks) {
            const int swz = ((ks * 4 + q) ^ fm7) * 8;   // halves
            const halfx8 a0 = *(const halfx8*)&As[(32 * wr + fm) * 64 + swz];
            const halfx8 a1 = *(const halfx8*)&As[(32 * wr + 16 + fm) * 64 + swz];
#pragma unroll
            for (int ct = 0; ct < 2; ++ct) {
                const int ng = wc * 32 + ct * 16 + fm;
                const halfx8 bg = *(const halfx8*)&Bs[ng * 64 + swz];
                const halfx8 bu = *(const halfx8*)&Bs[(64 + ng) * 64 + swz];
                accg[0][ct] = __builtin_amdgcn_mfma_f32_16x16x32_f16(a0, bg, accg[0][ct], 0, 0, 0);
                accg[1][ct] = __builtin_amdgcn_mfma_f32_16x16x32_f16(a1, bg, accg[1][ct], 0, 0, 0);
                accu[0][ct] = __builtin_amdgcn_mfma_f32_16x16x32_f16(a0, bu, accu[0][ct], 0, 0, 0);
                accu[1][ct] = __builtin_amdgcn_mfma_f32_16x16x32_f16(a1, bu, accu[1][ct], 0, 0, 0);
            }
        }
        __syncthreads();
    }

    // C/D layout: col = lane&15, row = q*4 + reg
#pragma unroll
    for (int rt = 0; rt < 2; ++rt)
#pragma unroll
        for (int r = 0; r < 4; ++r) {
            const int row = 32 * wr + 16 * rt + q * 4 + r;
            const int tk = toks[row];
            if (tk < 0) continue;
#pragma unroll
            for (int ct = 0; ct < 2; ++ct) {
                const float g = accg[rt][ct][r];
                const float u = accu[rt][ct][r];
                const float s = g / (1.f + __expf(-g)) * u;
                inter[(size_t)tk * I_DIM + n0 + wc * 32 + ct * 16 + fm] = (half_t)s;
            }
        }
}

// ---------------------------------------------------------------------------
// MFMA GEMM 2: out = inter @ down. Tile 64 x 128, BK=64, same staging scheme.
// ---------------------------------------------------------------------------
__global__ __launch_bounds__(256) void gemm2_mfma_kernel(
    const half_t* __restrict__ inter, const half_t* __restrict__ downT,
    const int* __restrict__ counts, const int* __restrict__ tok_list,
    float* __restrict__ out)
{
    const int e = blockIdx.z;
    const int count = counts[e];
    const int m0 = blockIdx.y * 64;
    if (m0 >= count) return;
    const int n0 = blockIdx.x * 128;

    __shared__ __align__(16) half_t As[64 * 64];
    __shared__ __align__(16) half_t Bs[128 * 64];
    __shared__ int toks[64];

    const int tid = threadIdx.x;
    if (tid < 64) {
        const int m = m0 + tid;
        toks[tid] = (m < count) ? tok_list[e * T_DIM + m] : -1;
    }
    __syncthreads();

    const half_t* De = downT + (size_t)e * H_DIM * I_DIM;

    const int lane = tid & 63;
    const int w = tid >> 6;
    const int lr = lane >> 3, lc = lane & 7;

    const half_t* aptr[2]; const half_t* bptr[4];
    half_t *alds[2], *blds[4];
#pragma unroll
    for (int j = 0; j < 2; ++j) {
        const int r = w * 16 + j * 8 + lr;
        const int cg = lc ^ (r & 7);
        const int tk = toks[r];
        aptr[j] = inter + (size_t)(tk < 0 ? 0 : tk) * I_DIM + cg * 8;
        alds[j] = &As[(w * 16 + j * 8) * 64];
    }
#pragma unroll
    for (int j = 0; j < 4; ++j) {
        const int n = w * 32 + j * 8 + lr;
        const int cg = lc ^ (n & 7);
        bptr[j] = De + (size_t)(n0 + n) * I_DIM + cg * 8;
        blds[j] = &Bs[(w * 32 + j * 8) * 64];
    }

    const floatx4 fzero = {0.f, 0.f, 0.f, 0.f};
    floatx4 acc[2][4];
#pragma unroll
    for (int i = 0; i < 2; ++i)
#pragma unroll
        for (int j = 0; j < 4; ++j) acc[i][j] = fzero;

    const int wr = w >> 1, wc = w & 1;
    const int fm = lane & 15, q = lane >> 4;
    const int fm7 = fm & 7;

    for (int k0 = 0; k0 < I_DIM; k0 += 64) {
#pragma unroll
        for (int j = 0; j < 2; ++j) GLOAD16(aptr[j] + k0, alds[j]);
#pragma unroll
        for (int j = 0; j < 4; ++j) GLOAD16(bptr[j] + k0, blds[j]);
        __syncthreads();

#pragma unroll
        for (int ks = 0; ks < 2; ++ks) {
            const int swz = ((ks * 4 + q) ^ fm7) * 8;
            const halfx8 a0 = *(const halfx8*)&As[(32 * wr + fm) * 64 + swz];
            const halfx8 a1 = *(const halfx8*)&As[(32 * wr + 16 + fm) * 64 + swz];
#pragma unroll
            for (int ct = 0; ct < 4; ++ct) {
                const halfx8 b = *(const halfx8*)&Bs[(wc * 64 + ct * 16 + fm) * 64 + swz];
                acc[0][ct] = __builtin_amdgcn_mfma_f32_16x16x32_f16(a0, b, acc[0][ct], 0, 0, 0);
                acc[1][ct] = __builtin_amdgcn_mfma_f32_16x16x32_f16(a1, b, acc[1][ct], 0, 0, 0);
            }
        }
        __syncthreads();
    }

#pragma unroll
    for (int rt = 0; rt < 2; ++rt)
#pragma unroll
        for (int r = 0; r < 4; ++r) {
            const int row = 32 * wr + 16 * rt + q * 4 + r;
            const int tk = toks[row];
            if (tk < 0) continue;
#pragma unroll
            for (int ct = 0; ct < 4; ++ct)
                out[(size_t)tk * H_DIM + n0 + wc * 64 + ct * 16 + fm] = acc[rt][ct][r];
        }
}

// ---------------------------------------------------------------------------
extern "C" void kernel_launch(void* const* d_in, const int* in_sizes, int n_in,
                              void* d_out, int out_size, void* d_ws, size_t ws_size,
                              hipStream_t stream)
{
    const float* x         = (const float*)d_in[0];
    const int*   token_ids = (const int*)  d_in[1];
    const float* mu        = (const float*)d_in[2];
    const float* gup       = (const float*)d_in[3];
    const float* down      = (const float*)d_in[4];
    const float* mu_w      = (const float*)d_in[5];
    float* out = (float*)d_out;

    char* ws = (char*)d_ws;
    int*    counts   = (int*)(ws + OFF_COUNTS);
    int*    tok_list = (int*)(ws + OFF_TOKL);
    half_t* xb       = (half_t*)(ws + OFF_XB);
    half_t* gupT     = (half_t*)(ws + OFF_GUPT);
    half_t* downT    = (half_t*)(ws + OFF_DOWNT);
    half_t* inter    = (half_t*)(ws + OFF_INTER);

    hipMemsetAsync(counts, 0, E_DIM * sizeof(int), stream);
    route_kernel<<<T_DIM, 256, 0, stream>>>(mu, token_ids, mu_w, counts, tok_list);
    prep_kernel<<<dim3(16, 16, 17), 256, 0, stream>>>(x, gup, down, xb, gupT, downT);
    gemm1_mfma_kernel<<<dim3(8, 64, 8), 256, 0, stream>>>(xb, gupT, counts, tok_list, inter);
    gemm2_mfma_kernel<<<dim3(8, 64, 8), 256, 0, stream>>>(inter, downT, counts, tok_list, out);
}

// Round 4
// 179.490 us; speedup vs baseline: 2.9546x; 1.2408x over previous
//
#include <hip/hip_runtime.h>
#include <cmath>

// Problem constants (fixed by the reference)
constexpr int T_DIM = 4096;
constexpr int H_DIM = 1024;
constexpr int E_DIM = 8;
constexpr int I_DIM = 512;   // 4096 / 8
constexpr int V_DIM = 32000;

typedef _Float16 half_t;
typedef __attribute__((ext_vector_type(8))) _Float16 halfx8;
typedef __attribute__((ext_vector_type(4))) _Float16 halfx4;
typedef __attribute__((ext_vector_type(4))) float floatx4;

// async global->LDS, 16 B per lane; LDS dest is wave-uniform base + lane*16
#define GLOAD16(g, l)                                                        \
    __builtin_amdgcn_global_load_lds(                                        \
        (const __attribute__((address_space(1))) void*)(g),                  \
        (__attribute__((address_space(3))) void*)(l), 16, 0, 0)

// ---------------------------------------------------------------------------
// Workspace layout (bytes)
// ---------------------------------------------------------------------------
constexpr size_t OFF_COUNTS = 0;                                          // E ints
constexpr size_t OFF_EID    = 1024;                                       // T ints (16 KB)
constexpr size_t OFF_TOKL   = OFF_EID + (size_t)T_DIM * 4;                // E*T ints (128 KB)
constexpr size_t OFF_XB     = OFF_TOKL + (size_t)E_DIM * T_DIM * 4;       // T*H f16 (8 MB)
constexpr size_t OFF_GUPT   = OFF_XB + (size_t)T_DIM * H_DIM * 2;         // E*2I*H f16 (16 MB)
constexpr size_t OFF_DOWNT  = OFF_GUPT + (size_t)E_DIM * 2 * I_DIM * H_DIM * 2; // E*H*I f16 (8 MB)
constexpr size_t OFF_INTER  = OFF_DOWNT + (size_t)E_DIM * H_DIM * I_DIM * 2;    // T*I f16 (4 MB)

// ---------------------------------------------------------------------------
// Routing phase A: expert_id[t] = argmax(one_hot(tid%8)*10 + mu@mu_w.T).
// One block per token; NO global atomics (they cost ~50 us in rounds 2-3:
// 4096 fetch-adds on 8 addresses serialize cross-XCD).
// ---------------------------------------------------------------------------
__global__ __launch_bounds__(256) void route_logits_kernel(
    const float* __restrict__ mu, const int* __restrict__ token_ids,
    const float* __restrict__ mu_w, int* __restrict__ expert_id)
{
    const int t = blockIdx.x;
    const int tid = threadIdx.x;

    const float4 m = *(const float4*)&mu[(size_t)t * H_DIM + tid * 4];
    float acc[E_DIM];
#pragma unroll
    for (int e = 0; e < E_DIM; ++e) {
        const float4 w = *(const float4*)&mu_w[e * H_DIM + tid * 4];
        acc[e] = m.x * w.x + m.y * w.y + m.z * w.z + m.w * w.w;
    }
#pragma unroll
    for (int e = 0; e < E_DIM; ++e) {
#pragma unroll
        for (int off = 32; off > 0; off >>= 1)
            acc[e] += __shfl_down(acc[e], off, 64);
    }
    __shared__ float part[4][E_DIM];
    const int lane = tid & 63, w = tid >> 6;
    if (lane == 0) {
#pragma unroll
        for (int e = 0; e < E_DIM; ++e) part[w][e] = acc[e];
    }
    __syncthreads();
    if (tid == 0) {
        int tk = token_ids[t];
        tk = min(max(tk, 0), V_DIM - 1);
        const int be = tk & (E_DIM - 1);
        float best = -1e30f; int bi = 0;
#pragma unroll
        for (int e = 0; e < E_DIM; ++e) {
            const float c = part[0][e] + part[1][e] + part[2][e] + part[3][e]
                          + (e == be ? 10.f : 0.f);
            if (c > best) { best = c; bi = e; }  // strict > keeps first max (jnp.argmax)
        }
        expert_id[t] = bi;
    }
}

// ---------------------------------------------------------------------------
// Fused prep: z<8 gup-transpose, z in [8,16) down-transpose, z==16 x-convert,
// z==17 routing scatter (single active block, LDS-atomic histogram).
// Transposes: dst[e][n][k] = (f16) src[e][k][n], 64x64 tiles.
// ---------------------------------------------------------------------------
__global__ __launch_bounds__(256) void prep_kernel(
    const float* __restrict__ x, const float* __restrict__ gup,
    const float* __restrict__ down, half_t* __restrict__ xb,
    half_t* __restrict__ gupT, half_t* __restrict__ downT,
    const int* __restrict__ expert_id, int* __restrict__ counts,
    int* __restrict__ tok_list)
{
    const int z = blockIdx.z, tid = threadIdx.x;

    if (z == 17) {  // routing scatter: one block, LDS atomics (fast, 1 CU)
        if (blockIdx.x != 0 || blockIdx.y != 0) return;
        __shared__ int cnt[E_DIM];
        if (tid < E_DIM) cnt[tid] = 0;
        __syncthreads();
        for (int i = tid; i < T_DIM; i += 256) {
            const int e = expert_id[i];
            const int pos = atomicAdd(&cnt[e], 1);   // LDS atomic
            tok_list[e * T_DIM + pos] = i;
        }
        __syncthreads();
        if (tid < E_DIM) counts[tid] = cnt[tid];
        return;
    }

    if (z == 16) {  // convert x -> f16
        const int blk = blockIdx.y * 16 + blockIdx.x;   // 0..255
#pragma unroll
        for (int p = 0; p < 16; ++p) {
            const size_t i = (size_t)blk * 16384 + p * 1024 + tid * 4;
            const float4 v = *(const float4*)&x[i];
            halfx4 h = { (half_t)v.x, (half_t)v.y, (half_t)v.z, (half_t)v.w };
            *(halfx4*)&xb[i] = h;
        }
        return;
    }

    __shared__ float tile[64][65];
    const float* se;  half_t* de;  int K;
    if (z < 8) {
        se = gup + (size_t)z * H_DIM * (2 * I_DIM);
        de = gupT + (size_t)z * (2 * I_DIM) * H_DIM;
        K = H_DIM;                       // 1024; N = 1024
    } else {
        if (blockIdx.y >= 8) return;     // K=512 -> only 8 y-tiles
        const int e = z - 8;
        se = down + (size_t)e * I_DIM * H_DIM;
        de = downT + (size_t)e * H_DIM * I_DIM;
        K = I_DIM;                       // 512; N = 1024
    }
    constexpr int N = 1024;
    const int n0 = blockIdx.x * 64, k0 = blockIdx.y * 64;
    const int c4 = (tid & 15) * 4, r0 = tid >> 4;
#pragma unroll
    for (int p = 0; p < 4; ++p) {
        const int r = r0 + p * 16;
        const float4 v = *(const float4*)&se[(size_t)(k0 + r) * N + n0 + c4];
        tile[r][c4 + 0] = v.x; tile[r][c4 + 1] = v.y;
        tile[r][c4 + 2] = v.z; tile[r][c4 + 3] = v.w;
    }
    __syncthreads();
#pragma unroll
    for (int p = 0; p < 4; ++p) {
        const int n = r0 + p * 16;
        const int kc = (tid & 15) * 4;
        halfx4 h = { (half_t)tile[kc + 0][n], (half_t)tile[kc + 1][n],
                     (half_t)tile[kc + 2][n], (half_t)tile[kc + 3][n] };
        *(halfx4*)&de[(size_t)(n0 + n) * K + k0 + kc] = h;
    }
}

// ---------------------------------------------------------------------------
// MFMA GEMM 1: inter = silu(x@Wg) * (x@Wu). Tile 64 tok x (64g + 64u), BK=64.
// Staging via global_load_lds(16B). LDS layout XOR-swizzled:
//   element (row r, 16B-chunk c) at byte offset r*128 + ((c ^ (r&7))*16)
// -> staging is lane-contiguous (HW requirement), frag reads conflict-free.
// ---------------------------------------------------------------------------
__global__ __launch_bounds__(256) void gemm1_mfma_kernel(
    const half_t* __restrict__ xb, const half_t* __restrict__ gupT,
    const int* __restrict__ counts, const int* __restrict__ tok_list,
    half_t* __restrict__ inter)
{
    const int e = blockIdx.z;
    const int count = counts[e];
    const int m0 = blockIdx.y * 64;
    if (m0 >= count) return;
    const int n0 = blockIdx.x * 64;  // gate col block

    __shared__ __align__(16) half_t As[64 * 64];
    __shared__ __align__(16) half_t Bs[128 * 64];
    __shared__ int toks[64];

    const int tid = threadIdx.x;
    if (tid < 64) {
        const int m = m0 + tid;
        toks[tid] = (m < count) ? tok_list[e * T_DIM + m] : -1;
    }
    __syncthreads();

    const half_t* We = gupT + (size_t)e * (2 * I_DIM) * H_DIM;

    const int lane = tid & 63;
    const int w = tid >> 6;
    const int lr = lane >> 3, lc = lane & 7;

    // per-lane staging pointers (row fixed across K-loop)
    const half_t* aptr[2]; const half_t* bptr[4];
    half_t *alds[2], *blds[4];
#pragma unroll
    for (int j = 0; j < 2; ++j) {                 // A rows [w*16, w*16+16)
        const int r = w * 16 + j * 8 + lr;
        const int cg = lc ^ (r & 7);
        const int tk = toks[r];
        aptr[j] = xb + (size_t)(tk < 0 ? 0 : tk) * H_DIM + cg * 8;
        alds[j] = &As[(w * 16 + j * 8) * 64];
    }
#pragma unroll
    for (int j = 0; j < 4; ++j) {                 // B rows [w*32, w*32+32)
        const int n = w * 32 + j * 8 + lr;
        const int col = (n < 64) ? (n0 + n) : (I_DIM + n0 + (n - 64));
        const int cg = lc ^ (n & 7);
        bptr[j] = We + (size_t)col * H_DIM + cg * 8;
        blds[j] = &Bs[(w * 32 + j * 8) * 64];
    }

    const floatx4 fzero = {0.f, 0.f, 0.f, 0.f};
    floatx4 accg[2][2], accu[2][2];
#pragma unroll
    for (int i = 0; i < 2; ++i)
#pragma unroll
        for (int j = 0; j < 2; ++j) { accg[i][j] = fzero; accu[i][j] = fzero; }

    const int wr = w >> 1, wc = w & 1;
    const int fm = lane & 15, q = lane >> 4;
    const int fm7 = fm & 7;

    for (int k0 = 0; k0 < H_DIM; k0 += 64) {
#pragma unroll
        for (int j = 0; j < 2; ++j) GLOAD16(aptr[j] + k0, alds[j]);
#pragma unroll
        for (int j = 0; j < 4; ++j) GLOAD16(bptr[j] + k0, blds[j]);
        __syncthreads();

#pragma unroll
        for (int ks = 0; ks < 2; ++ks) {
            const int swz = ((ks * 4 + q) ^ fm7) * 8;   // halves
            const halfx8 a0 = *(const halfx8*)&As[(32 * wr + fm) * 64 + swz];
            const halfx8 a1 = *(const halfx8*)&As[(32 * wr + 16 + fm) * 64 + swz];
#pragma unroll
            for (int ct = 0; ct < 2; ++ct) {
                const int ng = wc * 32 + ct * 16 + fm;
                const halfx8 bg = *(const halfx8*)&Bs[ng * 64 + swz];
                const halfx8 bu = *(const halfx8*)&Bs[(64 + ng) * 64 + swz];
                accg[0][ct] = __builtin_amdgcn_mfma_f32_16x16x32_f16(a0, bg, accg[0][ct], 0, 0, 0);
                accg[1][ct] = __builtin_amdgcn_mfma_f32_16x16x32_f16(a1, bg, accg[1][ct], 0, 0, 0);
                accu[0][ct] = __builtin_amdgcn_mfma_f32_16x16x32_f16(a0, bu, accu[0][ct], 0, 0, 0);
                accu[1][ct] = __builtin_amdgcn_mfma_f32_16x16x32_f16(a1, bu, accu[1][ct], 0, 0, 0);
            }
        }
        __syncthreads();
    }

    // C/D layout: col = lane&15, row = q*4 + reg
#pragma unroll
    for (int rt = 0; rt < 2; ++rt)
#pragma unroll
        for (int r = 0; r < 4; ++r) {
            const int row = 32 * wr + 16 * rt + q * 4 + r;
            const int tk = toks[row];
            if (tk < 0) continue;
#pragma unroll
            for (int ct = 0; ct < 2; ++ct) {
                const float g = accg[rt][ct][r];
                const float u = accu[rt][ct][r];
                const float s = g / (1.f + __expf(-g)) * u;
                inter[(size_t)tk * I_DIM + n0 + wc * 32 + ct * 16 + fm] = (half_t)s;
            }
        }
}

// ---------------------------------------------------------------------------
// MFMA GEMM 2: out = inter @ down. Tile 64 x 128, BK=64, same staging scheme.
// ---------------------------------------------------------------------------
__global__ __launch_bounds__(256) void gemm2_mfma_kernel(
    const half_t* __restrict__ inter, const half_t* __restrict__ downT,
    const int* __restrict__ counts, const int* __restrict__ tok_list,
    float* __restrict__ out)
{
    const int e = blockIdx.z;
    const int count = counts[e];
    const int m0 = blockIdx.y * 64;
    if (m0 >= count) return;
    const int n0 = blockIdx.x * 128;

    __shared__ __align__(16) half_t As[64 * 64];
    __shared__ __align__(16) half_t Bs[128 * 64];
    __shared__ int toks[64];

    const int tid = threadIdx.x;
    if (tid < 64) {
        const int m = m0 + tid;
        toks[tid] = (m < count) ? tok_list[e * T_DIM + m] : -1;
    }
    __syncthreads();

    const half_t* De = downT + (size_t)e * H_DIM * I_DIM;

    const int lane = tid & 63;
    const int w = tid >> 6;
    const int lr = lane >> 3, lc = lane & 7;

    const half_t* aptr[2]; const half_t* bptr[4];
    half_t *alds[2], *blds[4];
#pragma unroll
    for (int j = 0; j < 2; ++j) {
        const int r = w * 16 + j * 8 + lr;
        const int cg = lc ^ (r & 7);
        const int tk = toks[r];
        aptr[j] = inter + (size_t)(tk < 0 ? 0 : tk) * I_DIM + cg * 8;
        alds[j] = &As[(w * 16 + j * 8) * 64];
    }
#pragma unroll
    for (int j = 0; j < 4; ++j) {
        const int n = w * 32 + j * 8 + lr;
        const int cg = lc ^ (n & 7);
        bptr[j] = De + (size_t)(n0 + n) * I_DIM + cg * 8;
        blds[j] = &Bs[(w * 32 + j * 8) * 64];
    }

    const floatx4 fzero = {0.f, 0.f, 0.f, 0.f};
    floatx4 acc[2][4];
#pragma unroll
    for (int i = 0; i < 2; ++i)
#pragma unroll
        for (int j = 0; j < 4; ++j) acc[i][j] = fzero;

    const int wr = w >> 1, wc = w & 1;
    const int fm = lane & 15, q = lane >> 4;
    const int fm7 = fm & 7;

    for (int k0 = 0; k0 < I_DIM; k0 += 64) {
#pragma unroll
        for (int j = 0; j < 2; ++j) GLOAD16(aptr[j] + k0, alds[j]);
#pragma unroll
        for (int j = 0; j < 4; ++j) GLOAD16(bptr[j] + k0, blds[j]);
        __syncthreads();

#pragma unroll
        for (int ks = 0; ks < 2; ++ks) {
            const int swz = ((ks * 4 + q) ^ fm7) * 8;
            const halfx8 a0 = *(const halfx8*)&As[(32 * wr + fm) * 64 + swz];
            const halfx8 a1 = *(const halfx8*)&As[(32 * wr + 16 + fm) * 64 + swz];
#pragma unroll
            for (int ct = 0; ct < 4; ++ct) {
                const halfx8 b = *(const halfx8*)&Bs[(wc * 64 + ct * 16 + fm) * 64 + swz];
                acc[0][ct] = __builtin_amdgcn_mfma_f32_16x16x32_f16(a0, b, acc[0][ct], 0, 0, 0);
                acc[1][ct] = __builtin_amdgcn_mfma_f32_16x16x32_f16(a1, b, acc[1][ct], 0, 0, 0);
            }
        }
        __syncthreads();
    }

#pragma unroll
    for (int rt = 0; rt < 2; ++rt)
#pragma unroll
        for (int r = 0; r < 4; ++r) {
            const int row = 32 * wr + 16 * rt + q * 4 + r;
            const int tk = toks[row];
            if (tk < 0) continue;
#pragma unroll
            for (int ct = 0; ct < 4; ++ct)
                out[(size_t)tk * H_DIM + n0 + wc * 64 + ct * 16 + fm] = acc[rt][ct][r];
        }
}

// ---------------------------------------------------------------------------
extern "C" void kernel_launch(void* const* d_in, const int* in_sizes, int n_in,
                              void* d_out, int out_size, void* d_ws, size_t ws_size,
                              hipStream_t stream)
{
    const float* x         = (const float*)d_in[0];
    const int*   token_ids = (const int*)  d_in[1];
    const float* mu        = (const float*)d_in[2];
    const float* gup       = (const float*)d_in[3];
    const float* down      = (const float*)d_in[4];
    const float* mu_w      = (const float*)d_in[5];
    float* out = (float*)d_out;

    char* ws = (char*)d_ws;
    int*    counts    = (int*)(ws + OFF_COUNTS);
    int*    expert_id = (int*)(ws + OFF_EID);
    int*    tok_list  = (int*)(ws + OFF_TOKL);
    half_t* xb        = (half_t*)(ws + OFF_XB);
    half_t* gupT      = (half_t*)(ws + OFF_GUPT);
    half_t* downT     = (half_t*)(ws + OFF_DOWNT);
    half_t* inter     = (half_t*)(ws + OFF_INTER);

    route_logits_kernel<<<T_DIM, 256, 0, stream>>>(mu, token_ids, mu_w, expert_id);
    prep_kernel<<<dim3(16, 16, 18), 256, 0, stream>>>(
        x, gup, down, xb, gupT, downT, expert_id, counts, tok_list);
    gemm1_mfma_kernel<<<dim3(8, 64, 8), 256, 0, stream>>>(xb, gupT, counts, tok_list, inter);
    gemm2_mfma_kernel<<<dim3(8, 64, 8), 256, 0, stream>>>(inter, downT, counts, tok_list, out);
}

// Round 5
// 158.838 us; speedup vs baseline: 3.3387x; 1.1300x over previous
//
#include <hip/hip_runtime.h>
#include <cmath>

// Problem constants (fixed by the reference)
constexpr int T_DIM = 4096;
constexpr int H_DIM = 1024;
constexpr int E_DIM = 8;
constexpr int I_DIM = 512;   // 4096 / 8
constexpr int V_DIM = 32000;

typedef _Float16 half_t;
typedef __attribute__((ext_vector_type(8))) _Float16 halfx8;
typedef __attribute__((ext_vector_type(4))) _Float16 halfx4;
typedef __attribute__((ext_vector_type(4))) float floatx4;

// async global->LDS, 16 B per lane; LDS dest is wave-uniform base + lane*16
#define GLOAD16(g, l)                                                        \
    __builtin_amdgcn_global_load_lds(                                        \
        (const __attribute__((address_space(1))) void*)(g),                  \
        (__attribute__((address_space(3))) void*)(l), 16, 0, 0)

// ---------------------------------------------------------------------------
// Workspace layout (bytes)
// ---------------------------------------------------------------------------
constexpr size_t OFF_COUNTS = 0;                                          // E ints
constexpr size_t OFF_EID    = 1024;                                       // T ints (16 KB)
constexpr size_t OFF_TOKL   = OFF_EID + (size_t)T_DIM * 4;                // E*T ints (128 KB)
constexpr size_t OFF_XB     = OFF_TOKL + (size_t)E_DIM * T_DIM * 4;       // T*H f16 (8 MB)
constexpr size_t OFF_GUPT   = OFF_XB + (size_t)T_DIM * H_DIM * 2;         // E*2I*H f16 (16 MB)
constexpr size_t OFF_DOWNT  = OFF_GUPT + (size_t)E_DIM * 2 * I_DIM * H_DIM * 2; // E*H*I f16 (8 MB)
constexpr size_t OFF_INTER  = OFF_DOWNT + (size_t)E_DIM * H_DIM * I_DIM * 2;    // T*I f16 (4 MB)

// ---------------------------------------------------------------------------
// Routing phase A: expert_id[t] = argmax(one_hot(tid%8)*10 + mu@mu_w.T).
// One block per token; NO global atomics (4096 fetch-adds on 8 addresses
// serialize cross-XCD at ~100ns each = ~50 us, measured rounds 2-3).
// ---------------------------------------------------------------------------
__global__ __launch_bounds__(256) void route_logits_kernel(
    const float* __restrict__ mu, const int* __restrict__ token_ids,
    const float* __restrict__ mu_w, int* __restrict__ expert_id)
{
    const int t = blockIdx.x;
    const int tid = threadIdx.x;

    const float4 m = *(const float4*)&mu[(size_t)t * H_DIM + tid * 4];
    float acc[E_DIM];
#pragma unroll
    for (int e = 0; e < E_DIM; ++e) {
        const float4 w = *(const float4*)&mu_w[e * H_DIM + tid * 4];
        acc[e] = m.x * w.x + m.y * w.y + m.z * w.z + m.w * w.w;
    }
#pragma unroll
    for (int e = 0; e < E_DIM; ++e) {
#pragma unroll
        for (int off = 32; off > 0; off >>= 1)
            acc[e] += __shfl_down(acc[e], off, 64);
    }
    __shared__ float part[4][E_DIM];
    const int lane = tid & 63, w = tid >> 6;
    if (lane == 0) {
#pragma unroll
        for (int e = 0; e < E_DIM; ++e) part[w][e] = acc[e];
    }
    __syncthreads();
    if (tid == 0) {
        int tk = token_ids[t];
        tk = min(max(tk, 0), V_DIM - 1);
        const int be = tk & (E_DIM - 1);
        float best = -1e30f; int bi = 0;
#pragma unroll
        for (int e = 0; e < E_DIM; ++e) {
            const float c = part[0][e] + part[1][e] + part[2][e] + part[3][e]
                          + (e == be ? 10.f : 0.f);
            if (c > best) { best = c; bi = e; }  // strict > keeps first max (jnp.argmax)
        }
        expert_id[t] = bi;
    }
}

// ---------------------------------------------------------------------------
// Fused prep: z<8 gup-transpose, z in [8,16) down-transpose, z==16 x-convert,
// z==17 routing scatter (single active block, LDS-atomic histogram).
// Transposes: dst[e][n][k] = (f16) src[e][k][n], 64x64 tiles.
// ---------------------------------------------------------------------------
__global__ __launch_bounds__(256) void prep_kernel(
    const float* __restrict__ x, const float* __restrict__ gup,
    const float* __restrict__ down, half_t* __restrict__ xb,
    half_t* __restrict__ gupT, half_t* __restrict__ downT,
    const int* __restrict__ expert_id, int* __restrict__ counts,
    int* __restrict__ tok_list)
{
    const int z = blockIdx.z, tid = threadIdx.x;

    if (z == 17) {  // routing scatter: one block, LDS atomics (fast, 1 CU)
        if (blockIdx.x != 0 || blockIdx.y != 0) return;
        __shared__ int cnt[E_DIM];
        if (tid < E_DIM) cnt[tid] = 0;
        __syncthreads();
        for (int i = tid; i < T_DIM; i += 256) {
            const int e = expert_id[i];
            const int pos = atomicAdd(&cnt[e], 1);   // LDS atomic
            tok_list[e * T_DIM + pos] = i;
        }
        __syncthreads();
        if (tid < E_DIM) counts[tid] = cnt[tid];
        return;
    }

    if (z == 16) {  // convert x -> f16
        const int blk = blockIdx.y * 16 + blockIdx.x;   // 0..255
#pragma unroll
        for (int p = 0; p < 16; ++p) {
            const size_t i = (size_t)blk * 16384 + p * 1024 + tid * 4;
            const float4 v = *(const float4*)&x[i];
            halfx4 h = { (half_t)v.x, (half_t)v.y, (half_t)v.z, (half_t)v.w };
            *(halfx4*)&xb[i] = h;
        }
        return;
    }

    __shared__ float tile[64][65];
    const float* se;  half_t* de;  int K;
    if (z < 8) {
        se = gup + (size_t)z * H_DIM * (2 * I_DIM);
        de = gupT + (size_t)z * (2 * I_DIM) * H_DIM;
        K = H_DIM;                       // 1024; N = 1024
    } else {
        if (blockIdx.y >= 8) return;     // K=512 -> only 8 y-tiles
        const int e = z - 8;
        se = down + (size_t)e * I_DIM * H_DIM;
        de = downT + (size_t)e * H_DIM * I_DIM;
        K = I_DIM;                       // 512; N = 1024
    }
    constexpr int N = 1024;
    const int n0 = blockIdx.x * 64, k0 = blockIdx.y * 64;
    const int c4 = (tid & 15) * 4, r0 = tid >> 4;
#pragma unroll
    for (int p = 0; p < 4; ++p) {
        const int r = r0 + p * 16;
        const float4 v = *(const float4*)&se[(size_t)(k0 + r) * N + n0 + c4];
        tile[r][c4 + 0] = v.x; tile[r][c4 + 1] = v.y;
        tile[r][c4 + 2] = v.z; tile[r][c4 + 3] = v.w;
    }
    __syncthreads();
#pragma unroll
    for (int p = 0; p < 4; ++p) {
        const int n = r0 + p * 16;
        const int kc = (tid & 15) * 4;
        halfx4 h = { (half_t)tile[kc + 0][n], (half_t)tile[kc + 1][n],
                     (half_t)tile[kc + 2][n], (half_t)tile[kc + 3][n] };
        *(halfx4*)&de[(size_t)(n0 + n) * K + k0 + kc] = h;
    }
}

// ---------------------------------------------------------------------------
// MFMA GEMM 1: inter = silu(x@Wg) * (x@Wu). Tile 64 tok x (64g + 64u), BK=64.
// GRID: blockIdx.x = EXPERT (fastest-varying -> linear id % 8 = expert ->
// all blocks of expert e land on XCD e; per-XCD working set = 2 MB weights +
// ~1 MB gathered token rows, fits the 4 MB per-XCD L2. Round-robin-across-
// XCD dispatch of same-expert blocks was refetching ~16 MB/XCD from HBM).
// Staging via global_load_lds(16B), XOR-swizzled LDS (conflict-free frags).
// ---------------------------------------------------------------------------
__global__ __launch_bounds__(256) void gemm1_mfma_kernel(
    const half_t* __restrict__ xb, const half_t* __restrict__ gupT,
    const int* __restrict__ counts, const int* __restrict__ tok_list,
    half_t* __restrict__ inter)
{
    const int e = blockIdx.x;              // expert == XCD affinity
    const int count = counts[e];
    const int m0 = blockIdx.z * 64;
    if (m0 >= count) return;
    const int n0 = blockIdx.y * 64;        // gate col block

    __shared__ __align__(16) half_t As[64 * 64];
    __shared__ __align__(16) half_t Bs[128 * 64];
    __shared__ int toks[64];

    const int tid = threadIdx.x;
    if (tid < 64) {
        const int m = m0 + tid;
        toks[tid] = (m < count) ? tok_list[e * T_DIM + m] : -1;
    }
    __syncthreads();

    const half_t* We = gupT + (size_t)e * (2 * I_DIM) * H_DIM;

    const int lane = tid & 63;
    const int w = tid >> 6;
    const int lr = lane >> 3, lc = lane & 7;

    // per-lane staging pointers (row fixed across K-loop)
    const half_t* aptr[2]; const half_t* bptr[4];
    half_t *alds[2], *blds[4];
#pragma unroll
    for (int j = 0; j < 2; ++j) {                 // A rows [w*16, w*16+16)
        const int r = w * 16 + j * 8 + lr;
        const int cg = lc ^ (r & 7);
        const int tk = toks[r];
        aptr[j] = xb + (size_t)(tk < 0 ? 0 : tk) * H_DIM + cg * 8;
        alds[j] = &As[(w * 16 + j * 8) * 64];
    }
#pragma unroll
    for (int j = 0; j < 4; ++j) {                 // B rows [w*32, w*32+32)
        const int n = w * 32 + j * 8 + lr;
        const int col = (n < 64) ? (n0 + n) : (I_DIM + n0 + (n - 64));
        const int cg = lc ^ (n & 7);
        bptr[j] = We + (size_t)col * H_DIM + cg * 8;
        blds[j] = &Bs[(w * 32 + j * 8) * 64];
    }

    const floatx4 fzero = {0.f, 0.f, 0.f, 0.f};
    floatx4 accg[2][2], accu[2][2];
#pragma unroll
    for (int i = 0; i < 2; ++i)
#pragma unroll
        for (int j = 0; j < 2; ++j) { accg[i][j] = fzero; accu[i][j] = fzero; }

    const int wr = w >> 1, wc = w & 1;
    const int fm = lane & 15, q = lane >> 4;
    const int fm7 = fm & 7;

    for (int k0 = 0; k0 < H_DIM; k0 += 64) {
#pragma unroll
        for (int j = 0; j < 2; ++j) GLOAD16(aptr[j] + k0, alds[j]);
#pragma unroll
        for (int j = 0; j < 4; ++j) GLOAD16(bptr[j] + k0, blds[j]);
        __syncthreads();

#pragma unroll
        for (int ks = 0; ks < 2; ++ks) {
            const int swz = ((ks * 4 + q) ^ fm7) * 8;   // halves
            const halfx8 a0 = *(const halfx8*)&As[(32 * wr + fm) * 64 + swz];
            const halfx8 a1 = *(const halfx8*)&As[(32 * wr + 16 + fm) * 64 + swz];
#pragma unroll
            for (int ct = 0; ct < 2; ++ct) {
                const int ng = wc * 32 + ct * 16 + fm;
                const halfx8 bg = *(const halfx8*)&Bs[ng * 64 + swz];
                const halfx8 bu = *(const halfx8*)&Bs[(64 + ng) * 64 + swz];
                accg[0][ct] = __builtin_amdgcn_mfma_f32_16x16x32_f16(a0, bg, accg[0][ct], 0, 0, 0);
                accg[1][ct] = __builtin_amdgcn_mfma_f32_16x16x32_f16(a1, bg, accg[1][ct], 0, 0, 0);
                accu[0][ct] = __builtin_amdgcn_mfma_f32_16x16x32_f16(a0, bu, accu[0][ct], 0, 0, 0);
                accu[1][ct] = __builtin_amdgcn_mfma_f32_16x16x32_f16(a1, bu, accu[1][ct], 0, 0, 0);
            }
        }
        __syncthreads();
    }

    // C/D layout: col = lane&15, row = q*4 + reg
#pragma unroll
    for (int rt = 0; rt < 2; ++rt)
#pragma unroll
        for (int r = 0; r < 4; ++r) {
            const int row = 32 * wr + 16 * rt + q * 4 + r;
            const int tk = toks[row];
            if (tk < 0) continue;
#pragma unroll
            for (int ct = 0; ct < 2; ++ct) {
                const float g = accg[rt][ct][r];
                const float u = accu[rt][ct][r];
                const float s = g / (1.f + __expf(-g)) * u;
                inter[(size_t)tk * I_DIM + n0 + wc * 32 + ct * 16 + fm] = (half_t)s;
            }
        }
}

// ---------------------------------------------------------------------------
// MFMA GEMM 2: out = inter @ down. Tile 64 x 128, BK=64, same staging scheme.
// Same expert==blockIdx.x XCD-affinity grid.
// ---------------------------------------------------------------------------
__global__ __launch_bounds__(256) void gemm2_mfma_kernel(
    const half_t* __restrict__ inter, const half_t* __restrict__ downT,
    const int* __restrict__ counts, const int* __restrict__ tok_list,
    float* __restrict__ out)
{
    const int e = blockIdx.x;              // expert == XCD affinity
    const int count = counts[e];
    const int m0 = blockIdx.z * 64;
    if (m0 >= count) return;
    const int n0 = blockIdx.y * 128;

    __shared__ __align__(16) half_t As[64 * 64];
    __shared__ __align__(16) half_t Bs[128 * 64];
    __shared__ int toks[64];

    const int tid = threadIdx.x;
    if (tid < 64) {
        const int m = m0 + tid;
        toks[tid] = (m < count) ? tok_list[e * T_DIM + m] : -1;
    }
    __syncthreads();

    const half_t* De = downT + (size_t)e * H_DIM * I_DIM;

    const int lane = tid & 63;
    const int w = tid >> 6;
    const int lr = lane >> 3, lc = lane & 7;

    const half_t* aptr[2]; const half_t* bptr[4];
    half_t *alds[2], *blds[4];
#pragma unroll
    for (int j = 0; j < 2; ++j) {
        const int r = w * 16 + j * 8 + lr;
        const int cg = lc ^ (r & 7);
        const int tk = toks[r];
        aptr[j] = inter + (size_t)(tk < 0 ? 0 : tk) * I_DIM + cg * 8;
        alds[j] = &As[(w * 16 + j * 8) * 64];
    }
#pragma unroll
    for (int j = 0; j < 4; ++j) {
        const int n = w * 32 + j * 8 + lr;
        const int cg = lc ^ (n & 7);
        bptr[j] = De + (size_t)(n0 + n) * I_DIM + cg * 8;
        blds[j] = &Bs[(w * 32 + j * 8) * 64];
    }

    const floatx4 fzero = {0.f, 0.f, 0.f, 0.f};
    floatx4 acc[2][4];
#pragma unroll
    for (int i = 0; i < 2; ++i)
#pragma unroll
        for (int j = 0; j < 4; ++j) acc[i][j] = fzero;

    const int wr = w >> 1, wc = w & 1;
    const int fm = lane & 15, q = lane >> 4;
    const int fm7 = fm & 7;

    for (int k0 = 0; k0 < I_DIM; k0 += 64) {
#pragma unroll
        for (int j = 0; j < 2; ++j) GLOAD16(aptr[j] + k0, alds[j]);
#pragma unroll
        for (int j = 0; j < 4; ++j) GLOAD16(bptr[j] + k0, blds[j]);
        __syncthreads();

#pragma unroll
        for (int ks = 0; ks < 2; ++ks) {
            const int swz = ((ks * 4 + q) ^ fm7) * 8;
            const halfx8 a0 = *(const halfx8*)&As[(32 * wr + fm) * 64 + swz];
            const halfx8 a1 = *(const halfx8*)&As[(32 * wr + 16 + fm) * 64 + swz];
#pragma unroll
            for (int ct = 0; ct < 4; ++ct) {
                const halfx8 b = *(const halfx8*)&Bs[(wc * 64 + ct * 16 + fm) * 64 + swz];
                acc[0][ct] = __builtin_amdgcn_mfma_f32_16x16x32_f16(a0, b, acc[0][ct], 0, 0, 0);
                acc[1][ct] = __builtin_amdgcn_mfma_f32_16x16x32_f16(a1, b, acc[1][ct], 0, 0, 0);
            }
        }
        __syncthreads();
    }

#pragma unroll
    for (int rt = 0; rt < 2; ++rt)
#pragma unroll
        for (int r = 0; r < 4; ++r) {
            const int row = 32 * wr + 16 * rt + q * 4 + r;
            const int tk = toks[row];
            if (tk < 0) continue;
#pragma unroll
            for (int ct = 0; ct < 4; ++ct)
                out[(size_t)tk * H_DIM + n0 + wc * 64 + ct * 16 + fm] = acc[rt][ct][r];
        }
}

// ---------------------------------------------------------------------------
extern "C" void kernel_launch(void* const* d_in, const int* in_sizes, int n_in,
                              void* d_out, int out_size, void* d_ws, size_t ws_size,
                              hipStream_t stream)
{
    const float* x         = (const float*)d_in[0];
    const int*   token_ids = (const int*)  d_in[1];
    const float* mu        = (const float*)d_in[2];
    const float* gup       = (const float*)d_in[3];
    const float* down      = (const float*)d_in[4];
    const float* mu_w      = (const float*)d_in[5];
    float* out = (float*)d_out;

    char* ws = (char*)d_ws;
    int*    counts    = (int*)(ws + OFF_COUNTS);
    int*    expert_id = (int*)(ws + OFF_EID);
    int*    tok_list  = (int*)(ws + OFF_TOKL);
    half_t* xb        = (half_t*)(ws + OFF_XB);
    half_t* gupT      = (half_t*)(ws + OFF_GUPT);
    half_t* downT     = (half_t*)(ws + OFF_DOWNT);
    half_t* inter     = (half_t*)(ws + OFF_INTER);

    route_logits_kernel<<<T_DIM, 256, 0, stream>>>(mu, token_ids, mu_w, expert_id);
    prep_kernel<<<dim3(16, 16, 18), 256, 0, stream>>>(
        x, gup, down, xb, gupT, downT, expert_id, counts, tok_list);
    // expert on blockIdx.x: consecutive linear block ids round-robin the 8
    // XCDs, so expert e's blocks (and its L2 working set) pin to XCD e.
    gemm1_mfma_kernel<<<dim3(E_DIM, 8, T_DIM / 64), 256, 0, stream>>>(
        xb, gupT, counts, tok_list, inter);
    gemm2_mfma_kernel<<<dim3(E_DIM, 8, T_DIM / 64), 256, 0, stream>>>(
        inter, downT, counts, tok_list, out);
}